// Round 9
// baseline (399.813 us; speedup 1.0000x reference)
//
#include <hip/hip_runtime.h>

// RoiAlign / crop_and_resize: B=8, H=64, W=64, C=256, N=512, POOL=7
//
// R13: DIAGNOSTIC (deliberate, #2). R11's double-store probe failed to
// discriminate: +8us is the L2-absorbed rewrite cost (same dirty line),
// not the HBM write path. Two models remain consistent with ALL data:
//   A': kernel ~100-114us, fixed ~132us  (but then R8's fetch-elimination
//       null forces "reads were always L2-served" and ~60us is unexplained)
//   B : kernel ~45-50us,  fixed ~186us  (kernel near its ~35us write floor)
// Every structural rewrite (7 rounds) landed in the same +-4us band ->
// further blind edits are coin flips. This round: R10's exact structure
// (best, 231.5us) + each output value ALSO stored to nrep<=5 replica
// copies in d_ws (distinct addresses = genuine HBM writes; output itself
// untouched -> bit-identical). With 5 replicas the kernel exceeds the
// 124us fills under BOTH models and surfaces in top-5 WITH COUNTERS.
// Readings (K = kernel top-5 dur): K~200 => Model B (fixed~60, kernel~45,
// ~10us headroom); K~255+ => Model A' (fixed~8, kernel~100, ~60us
// headroom; VALUBusy/Occupancy/FETCH localize it). FETCH_SIZE ~100MB =>
// reads cache-served (explains read-side nulls); ~800MB => reopen reads.
// dur_us rises to ~385 BY DESIGN this round.

#define POOL  7
#define B_    8
#define H_    64
#define W_    64
#define C_    256
#define N_    512
#define CW    (C_ / 4)                   // 64 16B-quads per spatial pixel
#define ROWQ  (W_ * CW)                  // 4096 quads per fm row (64 KiB)
#define MAXI  3584                       // worst-case items in one list
#define OUT_ELEMS (B_ * N_ * POOL * POOL * C_)   // 51,380,224 floats
#define OUTQ  (OUT_ELEMS / 4)            // 12,845,056 v4f (205.5 MB)

typedef float v4f __attribute__((ext_vector_type(4)));
typedef unsigned short u16;

__global__ __launch_bounds__(512) void roialign_kernel(
    const float* __restrict__ fm,      // [B,H,W,C]
    const float* __restrict__ boxes,   // [B,N,4] x1,y1,x2,y2 normalized
    float* __restrict__ out,           // [B,N,POOL,POOL,C]
    v4f* __restrict__ wsrep,           // replica arena in d_ws (may be unused)
    int nrep)                          // number of full-output replicas
{
    extern __shared__ v4f lds[];           // [ROWQ] staged row bk (64 KiB)
    u16* list = (u16*)(lds + ROWQ);        // [MAXI] item codes (7 KiB)
    __shared__ int cnt;

    const int b    = blockIdx.x & 7;       // image -> XCD pin
    const int u    = blockIdx.x >> 3;      // 0..127
    const int bk   = u >> 1;               // fm row bucket 0..63
    const int half = u & 1;                // item-parity half (R10 split)
    const int tid  = threadIdx.x;          // 0..511
    const int wave = tid >> 6;             // 0..7
    const int lane = tid & 63;             // channel-quad
    const v4f* f4  = (const v4f*)fm;

    if (tid == 0) cnt = 0;
    __syncthreads();

    // ---- stage row bk (full channels, 64 KiB), coalesced ---------------
    {
        const int base0 = (b * H_ + bk) * ROWQ;
        #pragma unroll
        for (int k = 0; k < 8; ++k)
            lds[k * 512 + tid] = f4[base0 + k * 512 + tid];
    }

    // ---- fused bucketing: thread n scans its box's 7 samples -----------
    {
        const int n = tid;                 // 0..511
        const float by1 = boxes[(((b << 9) + n) << 2) + 1];
        const float by2 = boxes[(((b << 9) + n) << 2) + 3];
        const float sy  = (by2 - by1) * 63.0f / 6.0f;
        #pragma unroll
        for (int py = 0; py < POOL; ++py) {
            const float yv = by1 * 63.0f + (float)py * sy;
            const int y0  = (int)floorf(yv);
            const int bkk = min(max(y0, 0), H_ - 1);
            if (bkk == bk && (((n + py) & 1) == half)) {
                const int pos = atomicAdd(&cnt, 1);
                list[pos] = (u16)((n << 3) | py);
            }
        }
    }
    __syncthreads();

    const int nItems   = cnt;
    const int yb       = min(bk + 1, H_ - 1);
    const int rowBbase = (b * (H_ * W_) + yb * W_) * CW + lane;
    const float yfB    = (float)bk;
    v4f* out4 = (v4f*)out;

    for (int it = wave; it < nItems; it += 8) {
        const int code = __builtin_amdgcn_readfirstlane((int)list[it]);
        const int n  = code >> 3;
        const int py = code & 7;

        const float* box = boxes + (((b << 9) + n) << 2);
        const float bx1 = box[0], by1 = box[1], bx2 = box[2], by2 = box[3];

        // Match reference expression order exactly (x path), y via bucket:
        const float sy  = (by2 - by1) * 63.0f / 6.0f;
        const float sx  = (bx2 - bx1) * 63.0f / 6.0f;
        const float yv  = by1 * 63.0f + (float)py * sy;
        const float x0v = bx1 * 63.0f;

        const float fy = yv - yfB;          // yt == bk by bucketing
        const bool  vy = (yv >= 0.0f) && (yv <= 63.0f);

        const int obase = ((((b << 9) + n) * POOL + py) * POOL) * CW + lane;

        #pragma unroll
        for (int px = 0; px < POOL; ++px) {
            const float xv = x0v + (float)px * sx;
            const float xf = floorf(xv);
            const float fx = xv - xf;
            const int   x0 = (int)xf;
            const int   xl = min(max(x0,     0), W_ - 1);
            const int   xr = min(max(x0 + 1, 0), W_ - 1);
            const bool  valid = vy && (xv >= 0.0f) && (xv <= 63.0f);

            const v4f tl = lds[xl * CW + lane];          // row bk from LDS
            const v4f tr = lds[xr * CW + lane];
            const v4f bl = f4[rowBbase + xl * CW];       // row bk+1 from L2/L3
            const v4f br = f4[rowBbase + xr * CW];

            const v4f top = tl + (tr - tl) * fx;
            const v4f bot = bl + (br - bl) * fx;
            v4f o = top + (bot - top) * fy;
            if (!valid) o = (v4f)(0.0f);

            const int idx = obase + px * CW;
            out4[idx] = o;                 // real output (plain, L2 writeback)
            for (int r = 0; r < nrep; ++r) // replica stores: genuine HBM writes
                wsrep[idx + r * OUTQ] = o;
        }
    }
}

extern "C" void kernel_launch(void* const* d_in, const int* in_sizes, int n_in,
                              void* d_out, int out_size, void* d_ws, size_t ws_size,
                              hipStream_t stream) {
    const float* fm    = (const float*)d_in[0];   // [8,64,64,256] fp32
    const float* boxes = (const float*)d_in[1];   // [8,512,4] fp32
    float* out         = (float*)d_out;           // [8,512,7,7,256] fp32

    // Replica count: as many full output-sized copies as d_ws can hold, <=5.
    int nrep = 0;
    if (d_ws != nullptr)
        nrep = (int)(ws_size / ((size_t)OUTQ * sizeof(v4f)));
    if (nrep > 5) nrep = 5;

    // R10 grid: 2 blocks per (image,bucket) x 64 buckets x 8 images = 1024.
    const size_t ldsB = ROWQ * sizeof(v4f) + MAXI * sizeof(u16);
    roialign_kernel<<<H_ * 2 * B_, 512, ldsB, stream>>>(
        fm, boxes, out, (v4f*)d_ws, nrep);
}

// Round 10
// 241.632 us; speedup vs baseline: 1.6546x; 1.6546x over previous
//
#include <hip/hip_runtime.h>

// RoiAlign / crop_and_resize: B=8, H=64, W=64, C=256, N=512, POOL=7
//
// R14: quarter parity split. R13's replica diagnostic settled the model:
// fixed harness overhead = 182us (fill 124 + ~58 unseen); real kernel
// times: R4=60, R9=51.6, R10=49.5 (best), R12=53. FETCH=92.5MB on 822MB
// of issued reads -> gather is ~89% L2/L3-served (fm = 4MiB/image = one
// pinned XCD L2) — reads were never the bottleneck. Store path ~4.9TB/s,
// floor = 205.5MB writes + ~32MB fetch ~= 36-40us.
// Attackable gap: tail imbalance (bucket sizes vary ~3x). The split
// granularity lever is proven (R12 1-way=53 < R10 2-way=49.5). This
// round: widen 2->4 parity classes ((n+py)&3), 2048 blocks, same
// 72.7KiB LDS -> still 2 blocks/CU, 8 scheduling rounds, quarter tails.
// Staging duplication stays cheap: parity siblings are co-resident on
// the same XCD -> later stages hit L2.
// Keep: fused bucketing, tl/tr from LDS, bl/br from L2/L3, plain
// writeback stores, image->XCD pin, exact reference x-path math,
// y via bucket identity (yt==bk, fy=yv-bk).

#define POOL  7
#define B_    8
#define H_    64
#define W_    64
#define C_    256
#define N_    512
#define CW    (C_ / 4)                   // 64 16B-quads per spatial pixel
#define ROWQ  (W_ * CW)                  // 4096 quads per fm row (64 KiB)
#define MAXI  3584                       // safe bound for one list

typedef float v4f __attribute__((ext_vector_type(4)));
typedef unsigned short u16;

__global__ __launch_bounds__(512) void roialign_kernel(
    const float* __restrict__ fm,      // [B,H,W,C]
    const float* __restrict__ boxes,   // [B,N,4] x1,y1,x2,y2 normalized
    float* __restrict__ out)           // [B,N,POOL,POOL,C]
{
    extern __shared__ v4f lds[];           // [ROWQ] staged row bk (64 KiB)
    u16* list = (u16*)(lds + ROWQ);        // [MAXI] item codes (7 KiB)
    __shared__ int cnt;

    const int b    = blockIdx.x & 7;       // image -> XCD pin
    const int u    = blockIdx.x >> 3;      // 0..255
    const int bk   = u >> 2;               // fm row bucket 0..63
    const int quarter = u & 3;             // item-parity quarter
    const int tid  = threadIdx.x;          // 0..511
    const int wave = tid >> 6;             // 0..7
    const int lane = tid & 63;             // channel-quad
    const v4f* f4  = (const v4f*)fm;

    if (tid == 0) cnt = 0;
    __syncthreads();

    // ---- stage row bk (full channels, 64 KiB), coalesced ---------------
    {
        const int base0 = (b * H_ + bk) * ROWQ;
        #pragma unroll
        for (int k = 0; k < 8; ++k)
            lds[k * 512 + tid] = f4[base0 + k * 512 + tid];
    }

    // ---- fused bucketing: thread n scans its box's 7 samples -----------
    {
        const int n = tid;                 // 0..511
        const float by1 = boxes[(((b << 9) + n) << 2) + 1];
        const float by2 = boxes[(((b << 9) + n) << 2) + 3];
        const float sy  = (by2 - by1) * 63.0f / 6.0f;
        #pragma unroll
        for (int py = 0; py < POOL; ++py) {
            const float yv = by1 * 63.0f + (float)py * sy;
            const int y0  = (int)floorf(yv);
            const int bkk = min(max(y0, 0), H_ - 1);
            if (bkk == bk && (((n + py) & 3) == quarter)) {
                const int pos = atomicAdd(&cnt, 1);
                list[pos] = (u16)((n << 3) | py);
            }
        }
    }
    __syncthreads();

    const int nItems   = cnt;
    const int yb       = min(bk + 1, H_ - 1);
    const int rowBbase = (b * (H_ * W_) + yb * W_) * CW + lane;
    const float yfB    = (float)bk;

    for (int it = wave; it < nItems; it += 8) {
        const int code = __builtin_amdgcn_readfirstlane((int)list[it]);
        const int n  = code >> 3;
        const int py = code & 7;

        const float* box = boxes + (((b << 9) + n) << 2);
        const float bx1 = box[0], by1 = box[1], bx2 = box[2], by2 = box[3];

        // Match reference expression order exactly (x path), y via bucket:
        const float sy  = (by2 - by1) * 63.0f / 6.0f;
        const float sx  = (bx2 - bx1) * 63.0f / 6.0f;
        const float yv  = by1 * 63.0f + (float)py * sy;
        const float x0v = bx1 * 63.0f;

        // yt == bk by bucketing; fy relative to bk is continuous across
        // any 1-ulp build/process divergence at integer boundaries.
        const float fy = yv - yfB;
        const bool  vy = (yv >= 0.0f) && (yv <= 63.0f);

        v4f* o4 = (v4f*)out + ((((b << 9) + n) * POOL + py) * POOL) * CW + lane;

        #pragma unroll
        for (int px = 0; px < POOL; ++px) {
            const float xv = x0v + (float)px * sx;
            const float xf = floorf(xv);
            const float fx = xv - xf;
            const int   x0 = (int)xf;
            const int   xl = min(max(x0,     0), W_ - 1);
            const int   xr = min(max(x0 + 1, 0), W_ - 1);
            const bool  valid = vy && (xv >= 0.0f) && (xv <= 63.0f);

            const v4f tl = lds[xl * CW + lane];          // row bk from LDS
            const v4f tr = lds[xr * CW + lane];
            const v4f bl = f4[rowBbase + xl * CW];       // row bk+1 from L2/L3
            const v4f br = f4[rowBbase + xr * CW];

            const v4f top = tl + (tr - tl) * fx;
            const v4f bot = bl + (br - bl) * fx;
            v4f o = top + (bot - top) * fy;
            if (!valid) o = (v4f)(0.0f);

            o4[px * CW] = o;               // plain store: completes at L2
        }
    }
}

extern "C" void kernel_launch(void* const* d_in, const int* in_sizes, int n_in,
                              void* d_out, int out_size, void* d_ws, size_t ws_size,
                              hipStream_t stream) {
    const float* fm    = (const float*)d_in[0];   // [8,64,64,256] fp32
    const float* boxes = (const float*)d_in[1];   // [8,512,4] fp32
    float* out         = (float*)d_out;           // [8,512,7,7,256] fp32

    // 4 blocks per (image,bucket): 64 x 4 x 8 = 2048 blocks.
    // Dynamic LDS: 64 KiB row + 7 KiB list = 72704 B -> 2 blocks/CU.
    const size_t ldsB = ROWQ * sizeof(v4f) + MAXI * sizeof(u16);
    roialign_kernel<<<H_ * 4 * B_, 512, ldsB, stream>>>(fm, boxes, out);
}